// Round 10
// baseline (233.403 us; speedup 1.0000x reference)
//
#include <hip/hip_runtime.h>
#include <hip/hip_bf16.h>

#define NNODES 10000
#define NB 8
#define NF 128
#define NE 160000

typedef __attribute__((ext_vector_type(8))) short  short8;   // 8 bf16 (A/B frag)
typedef __attribute__((ext_vector_type(8))) unsigned short ushort8;
typedef __attribute__((ext_vector_type(4))) float  f32x4;    // MFMA acc

// fp32 -> bf16 (RNE) scalar
__device__ __forceinline__ unsigned short f2b(float f) {
    union { float f; unsigned u; } v; v.f = f;
    unsigned r = v.u + 0x7FFF + ((v.u >> 16) & 1);
    return (unsigned short)(r >> 16);
}
// packed pair fp32 -> bf16x2 (v_cvt_pk_bf16_f32)
__device__ __forceinline__ unsigned int f2b2(float a, float b) {
    union { __hip_bfloat162 h; unsigned int u; } v;
    v.h = __float22bfloat162_rn(make_float2(a, b));
    return v.u;
}
__device__ __forceinline__ float b2f_lo(unsigned u) {
    union { unsigned u; float f; } v; v.u = u << 16; return v.f;
}
__device__ __forceinline__ float b2f_hi(unsigned u) {
    union { unsigned u; float f; } v; v.u = u & 0xffff0000u; return v.f;
}

// ---------------- preprocessing ----------------

__global__ void k_count(const int* __restrict__ ei, int* __restrict__ cnt) {
    int e = blockIdx.x * blockDim.x + threadIdx.x;
    if (e < NE) atomicAdd(&cnt[ei[NE + e]], 1);
}

// one-block scan of cnt -> row_ptr (+ dinv); wave-shuffle based, 2 barriers
__global__ __launch_bounds__(1024) void k_scan(const int* __restrict__ cnt,
                                               int* __restrict__ row_ptr,
                                               float* __restrict__ dinv) {
    __shared__ int wsum[16];
    const int t = threadIdx.x;
    const int lane = t & 63, wv = t >> 6;
    const int CH = 10;                       // 1024*10 >= NNODES
    int lo = t * CH;
    int hi = min(lo + CH, NNODES);
    int c10[CH];
    int s = 0;
    for (int i = lo; i < hi; i++) {
        int c = cnt[i];
        c10[i - lo] = c;
        dinv[i] = rsqrtf((float)(c + 1));
        s += c;
    }
    int v = s;                               // inclusive scan within wave
    #pragma unroll
    for (int m = 1; m < 64; m <<= 1) {
        int o = __shfl_up(v, m);
        if (lane >= m) v += o;
    }
    if (lane == 63) wsum[wv] = v;
    __syncthreads();
    if (t < 16) {
        int w = wsum[t];
        #pragma unroll
        for (int m = 1; m < 16; m <<= 1) {
            int o = __shfl_up(w, m);
            if (t >= m) w += o;
        }
        wsum[t] = w;
    }
    __syncthreads();
    int base = v - s + (wv ? wsum[wv - 1] : 0);   // exclusive prefix of this chunk
    for (int i = lo; i < hi; i++) { row_ptr[i] = base; base += c10[i - lo]; }
    if (t == 1023) row_ptr[NNODES] = wsum[15];
}

// CSR scatter; edge[pos] = src(16b) | bf16(w) << 16   (4 B per edge)
__global__ void k_scatter(const int* __restrict__ ei, const int* __restrict__ row_ptr,
                          int* __restrict__ fill, const float* __restrict__ dinv,
                          unsigned int* __restrict__ edge) {
    int e = blockIdx.x * blockDim.x + threadIdx.x;
    if (e >= NE) return;
    int s = ei[e];
    int d = ei[NE + e];
    int pos = row_ptr[d] + atomicAdd(&fill[d], 1);
    edge[pos] = (unsigned)s | ((unsigned)f2b(dinv[s] * dinv[d]) << 16);
}

// both W -> Wt bf16 transposed (runs AFTER scan/scatter: Wt alias cnt/fill)
__global__ void k_wt2(const float* __restrict__ W1, unsigned short* __restrict__ Wt1,
                      const float* __restrict__ W2, unsigned short* __restrict__ Wt2) {
    int bid = blockIdx.x;
    const float* W = (bid < 64) ? W1 : W2;
    unsigned short* Wt = (bid < 64) ? Wt1 : Wt2;
    int id = (bid & 63) * 256 + threadIdx.x;   // 16384
    int n = id >> 7, k = id & 127;
    Wt[(size_t)n * 128 + k] = f2b(W[(size_t)k * 128 + n]);
}

// ---------------- bf16 MFMA matmul ----------------
// C = A[80000,128] @ W, bf16 out row gm -> Cn + gm*128 ([B,N,128] order).
// A-op fragments (Wt) loaded DIRECTLY from global: all blocks read the same
// 32 KB, which lives in each CU's 32 KB L1 — no LDS staging, no bank
// conflicts (prior 136-ushort LDS stride gave 8-way conflicts on ds_read_b128),
// one barrier instead of three. LDS used only for the coalesced C write-out.
template <bool ABF16>
__global__ __launch_bounds__(256) void k_mm_mfma(const void* __restrict__ Ap,
                                                 const unsigned short* __restrict__ Wt,
                                                 unsigned short* __restrict__ Cn) {
    __shared__ unsigned short clds[128 * 136];  // C-stage only (34.8 KB)
    const int t = threadIdx.x;
    const int wid = t >> 6, lane = t & 63;
    const int quad = lane >> 4, l16 = lane & 15;
    const int m0 = blockIdx.x * 128 + (wid & 1) * 64;  // act row base for this wave
    const int nb = (wid >> 1) * 64;                    // feature base
    const int kq = quad * 8;

    f32x4 acc[4][4] = {};

    #pragma unroll
    for (int ks = 0; ks < 128; ks += 32) {
        short8 af[4];
        #pragma unroll
        for (int ni = 0; ni < 4; ni++)
            af[ni] = *(const short8*)(Wt + (size_t)(nb + ni * 16 + l16) * 128 + ks + kq);
        short8 bf[4];
        #pragma unroll
        for (int mi = 0; mi < 4; mi++) {
            const size_t row = (size_t)(m0 + mi * 16 + l16);
            if constexpr (ABF16) {
                bf[mi] = *(const short8*)((const unsigned short*)Ap + row * 128 + ks + kq);
            } else {
                const float* p = (const float*)Ap + row * 128 + ks + kq;
                float4 u0 = *(const float4*)p;
                float4 u1 = *(const float4*)(p + 4);
                union { uint4 u4; short8 s8; } cv;
                cv.u4.x = f2b2(u0.x, u0.y); cv.u4.y = f2b2(u0.z, u0.w);
                cv.u4.z = f2b2(u1.x, u1.y); cv.u4.w = f2b2(u1.z, u1.w);
                bf[mi] = cv.s8;
            }
        }
        #pragma unroll
        for (int mi = 0; mi < 4; mi++)
            #pragma unroll
            for (int ni = 0; ni < 4; ni++)
                acc[mi][ni] = __builtin_amdgcn_mfma_f32_16x16x32_bf16(
                    af[ni], bf[mi], acc[mi][ni], 0, 0, 0);
    }

    // ---- epilogue: stage 128x128 bf16 tile in LDS, coalesced stores ----
    {
        const int rbase = (wid & 1) * 64;
        #pragma unroll
        for (int mi = 0; mi < 4; mi++) {
            int rr = rbase + mi * 16 + l16;
            #pragma unroll
            for (int ni = 0; ni < 4; ni++) {
                uint2 p;
                p.x = f2b2(acc[mi][ni][0], acc[mi][ni][1]);
                p.y = f2b2(acc[mi][ni][2], acc[mi][ni][3]);
                *(uint2*)(clds + rr * 136 + nb + ni * 16 + quad * 4) = p;
            }
        }
    }
    __syncthreads();
    {
        const int r = t >> 1, h = t & 1;     // 128 rows x 2 halves of 128 B
        size_t gm = (size_t)blockIdx.x * 128 + r;   // row index in [B,N] order
        unsigned short* dst = Cn + gm * 128 + h * 64;
        const unsigned short* srow = clds + r * 136 + h * 64;
        #pragma unroll
        for (int i = 0; i < 8; i++)
            *(ushort8*)(dst + i * 8) = *(const ushort8*)(srow + i * 8);
    }
}

// ---------------- aggregation ----------------
// hNu: bf16 [B, N, 128] viewed as uint. One WAVE per (node, batch); lane holds
// feats {2*lane, 2*lane+1}; per edge one 256 B contiguous gather.
// b = blockIdx & 7 (XCD heuristic). Edges 4 B packed (src | bf16 w).

__global__ __launch_bounds__(256) void k_agg_relu(const unsigned int* __restrict__ hNu,
                                                  const float* __restrict__ bias,
                                                  const int* __restrict__ row_ptr,
                                                  const unsigned int* __restrict__ edge,
                                                  const float* __restrict__ dinv,
                                                  unsigned int* __restrict__ h1u) {
    const int t = threadIdx.x;
    const int b = blockIdx.x & 7;
    const int g = blockIdx.x >> 3;
    const int wid = __builtin_amdgcn_readfirstlane(t >> 6);
    const int lane = t & 63;
    const int n = g * 4 + wid;

    const unsigned int* base = hNu + (size_t)b * NNODES * 64 + lane;  // + s*64
    float di = dinv[n];
    float wself = di * di;
    unsigned int u = base[(size_t)n * 64];
    float a0 = b2f_lo(u) * wself;
    float a1 = b2f_hi(u) * wself;

    int e = row_ptr[n], e1 = row_ptr[n + 1];
    for (; e + 8 <= e1; e += 8) {
        unsigned int E[8];
        #pragma unroll
        for (int j = 0; j < 8; j++) E[j] = edge[e + j];
        unsigned int U[8];
        #pragma unroll
        for (int j = 0; j < 8; j++) U[j] = base[(size_t)(E[j] & 0xffffu) * 64];
        #pragma unroll
        for (int j = 0; j < 8; j++) {
            float w = b2f_hi(E[j]);
            a0 = fmaf(b2f_lo(U[j]), w, a0);
            a1 = fmaf(b2f_hi(U[j]), w, a1);
        }
    }
    for (; e + 4 <= e1; e += 4) {
        unsigned int E[4];
        #pragma unroll
        for (int j = 0; j < 4; j++) E[j] = edge[e + j];
        unsigned int U[4];
        #pragma unroll
        for (int j = 0; j < 4; j++) U[j] = base[(size_t)(E[j] & 0xffffu) * 64];
        #pragma unroll
        for (int j = 0; j < 4; j++) {
            float w = b2f_hi(E[j]);
            a0 = fmaf(b2f_lo(U[j]), w, a0);
            a1 = fmaf(b2f_hi(U[j]), w, a1);
        }
    }
    for (; e < e1; ++e) {
        unsigned int E = edge[e];
        float w = b2f_hi(E);
        unsigned int uu = base[(size_t)(E & 0xffffu) * 64];
        a0 = fmaf(b2f_lo(uu), w, a0);
        a1 = fmaf(b2f_hi(uu), w, a1);
    }
    a0 = fmaxf(a0 + bias[lane * 2], 0.f);
    a1 = fmaxf(a1 + bias[lane * 2 + 1], 0.f);
    __builtin_nontemporal_store(f2b2(a0, a1), &h1u[((size_t)b * NNODES + n) * 64 + lane]);
}

__global__ __launch_bounds__(256) void k_agg_ln(const unsigned int* __restrict__ hNu,
                                                const float* __restrict__ bias,
                                                const int* __restrict__ row_ptr,
                                                const unsigned int* __restrict__ edge,
                                                const float* __restrict__ dinv,
                                                const float* __restrict__ ln_w,
                                                const float* __restrict__ ln_b,
                                                float* __restrict__ out) {
    const int t = threadIdx.x;
    const int b = blockIdx.x & 7;
    const int g = blockIdx.x >> 3;
    const int wid = __builtin_amdgcn_readfirstlane(t >> 6);
    const int lane = t & 63;
    const int n = g * 4 + wid;

    const unsigned int* base = hNu + (size_t)b * NNODES * 64 + lane;
    float di = dinv[n];
    float wself = di * di;
    unsigned int u = base[(size_t)n * 64];
    float a0 = b2f_lo(u) * wself;
    float a1 = b2f_hi(u) * wself;

    int e = row_ptr[n], e1 = row_ptr[n + 1];
    for (; e + 8 <= e1; e += 8) {
        unsigned int E[8];
        #pragma unroll
        for (int j = 0; j < 8; j++) E[j] = edge[e + j];
        unsigned int U[8];
        #pragma unroll
        for (int j = 0; j < 8; j++) U[j] = base[(size_t)(E[j] & 0xffffu) * 64];
        #pragma unroll
        for (int j = 0; j < 8; j++) {
            float w = b2f_hi(E[j]);
            a0 = fmaf(b2f_lo(U[j]), w, a0);
            a1 = fmaf(b2f_hi(U[j]), w, a1);
        }
    }
    for (; e + 4 <= e1; e += 4) {
        unsigned int E[4];
        #pragma unroll
        for (int j = 0; j < 4; j++) E[j] = edge[e + j];
        unsigned int U[4];
        #pragma unroll
        for (int j = 0; j < 4; j++) U[j] = base[(size_t)(E[j] & 0xffffu) * 64];
        #pragma unroll
        for (int j = 0; j < 4; j++) {
            float w = b2f_hi(E[j]);
            a0 = fmaf(b2f_lo(U[j]), w, a0);
            a1 = fmaf(b2f_hi(U[j]), w, a1);
        }
    }
    for (; e < e1; ++e) {
        unsigned int E = edge[e];
        float w = b2f_hi(E);
        unsigned int uu = base[(size_t)(E & 0xffffu) * 64];
        a0 = fmaf(b2f_lo(uu), w, a0);
        a1 = fmaf(b2f_hi(uu), w, a1);
    }
    a0 += bias[lane * 2];
    a1 += bias[lane * 2 + 1];

    // LayerNorm over 128 feats spread across the 64-lane wave (2/lane)
    float s1 = a0 + a1;
    float s2 = a0 * a0 + a1 * a1;
    #pragma unroll
    for (int m = 1; m < 64; m <<= 1) {
        s1 += __shfl_xor(s1, m);
        s2 += __shfl_xor(s2, m);
    }
    float mu = s1 * (1.f / NF);
    float var = s2 * (1.f / NF) - mu * mu;
    float rs = rsqrtf(var + 1e-5f);

    float o0 = (a0 - mu) * rs * ln_w[lane * 2] + ln_b[lane * 2];
    float o1 = (a1 - mu) * rs * ln_w[lane * 2 + 1] + ln_b[lane * 2 + 1];
    float* dst = out + ((size_t)b * NNODES + n) * 128 + lane * 2;
    __builtin_nontemporal_store(o0, dst);
    __builtin_nontemporal_store(o1, dst + 1);
}

// ---------------- launch ----------------

extern "C" void kernel_launch(void* const* d_in, const int* in_sizes, int n_in,
                              void* d_out, int out_size, void* d_ws, size_t ws_size,
                              hipStream_t stream) {
    const float* x    = (const float*)d_in[0];
    const int*   ei   = (const int*)d_in[1];   // int32 [2, E]
    const float* W1   = (const float*)d_in[2];
    const float* b1   = (const float*)d_in[3];
    const float* W2   = (const float*)d_in[4];
    const float* b2   = (const float*)d_in[5];
    const float* ln_w = (const float*)d_in[6];
    const float* ln_b = (const float*)d_in[7];
    float* out = (float*)d_out;

    // workspace layout. Wt1/Wt2 alias cnt/fill (dead after scan/scatter; k_wt2 runs after).
    char* ws = (char*)d_ws;
    int*            cnt     = (int*)(ws + 0);          // N ints; later Wt1 (32 KB)
    int*            fill    = (int*)(ws + 40192);      // N ints; later Wt2 (32 KB)
    int*            row_ptr = (int*)(ws + 80384);      // N+1 ints
    float*          dinv    = (float*)(ws + 120832);   // N floats
    unsigned int*   edge    = (unsigned int*)(ws + 161024);     // E uint (640 KB)
    unsigned short* hA16    = (unsigned short*)(ws + 1441024);  // [B,N,128] bf16 (20.48 MB)
    unsigned short* h1b     = (unsigned short*)(ws + 21921024); // [B,N,128] bf16 (20.48 MB)
    unsigned short* Wt1     = (unsigned short*)cnt;
    unsigned short* Wt2     = (unsigned short*)fill;

    // ---- CSR (by dst) + symmetric norm weights ----
    hipMemsetAsync(ws, 0, 80384, stream);              // zero cnt + fill
    k_count  <<<(NE + 255) / 256, 256, 0, stream>>>(ei, cnt);
    k_scan   <<<1, 1024, 0, stream>>>(cnt, row_ptr, dinv);
    k_scatter<<<(NE + 255) / 256, 256, 0, stream>>>(ei, row_ptr, fill, dinv, edge);
    k_wt2    <<<128, 256, 0, stream>>>(W1, Wt1, W2, Wt2);

    // ---- layer 1 ----
    k_mm_mfma<false><<<(NB * NNODES) / 128, 256, 0, stream>>>(x, Wt1, hA16);
    k_agg_relu<<<(NNODES / 4) * NB, 256, 0, stream>>>((const unsigned int*)hA16, b1,
                                                      row_ptr, edge, dinv,
                                                      (unsigned int*)h1b);

    // ---- layer 2 ----
    k_mm_mfma<true><<<(NB * NNODES) / 128, 256, 0, stream>>>(h1b, Wt2, hA16);
    k_agg_ln<<<(NNODES / 4) * NB, 256, 0, stream>>>((const unsigned int*)hA16, b2,
                                                    row_ptr, edge, dinv,
                                                    ln_w, ln_b, out);
}